// Round 7
// baseline (883.391 us; speedup 1.0000x reference)
//
#include <hip/hip_runtime.h>

// ---------------- dtype helpers ----------------
__device__ __forceinline__ float b2f(unsigned short u) {
  return __uint_as_float(((unsigned)u) << 16);
}
__device__ __forceinline__ unsigned short f2b(float f) {
  unsigned u = __float_as_uint(f);
  return (unsigned short)((u + 0x7FFFu + ((u >> 16) & 1u)) >> 16);
}
// load element i of a tensor that is bf16 (isb=1) or fp32 (isb=0)
__device__ __forceinline__ float gload(const void* p, int i, int isb) {
  return isb ? b2f(((const unsigned short*)p)[i]) : ((const float*)p)[i];
}
// monotone bijection float -> uint32 (order-preserving incl. negatives)
__device__ __forceinline__ unsigned tokey(float f) {
  unsigned u = __float_as_uint(f);
  return u ^ (unsigned)(((int)u >> 31) | 0x80000000u);
}

// ---------------- dtype detector (dataset proven fp32; kept for safety) ----------------
__global__ void k_detect(const void* x, int* flag) {
  int tid = threadIdx.x;  // 1 wave
  unsigned short u = ((const unsigned short*)x)[2 * tid];
  int e = (u >> 7) & 0xFF;
  bool sane = (e >= 100 && e <= 140);
  unsigned long long m = __ballot(sane);
  if (tid == 0) *flag = (__popcll(m) >= 40) ? 1 : 0;
}

// ---------------- k_prep: WtF[i][u] = fc1_w[u][i] * (mask<0.5), f32 transposed ----------------
__global__ __launch_bounds__(256) void k_prep(const void* __restrict__ fc1w,
                                              const void* __restrict__ mraw,
                                              float* __restrict__ WtF,
                                              const int* __restrict__ flag) {
  __shared__ float tile[64][65];
  const int isb = *flag;
  const int i0 = blockIdx.x * 64;  // K index (9216)
  const int u0 = blockIdx.y * 64;  // unit index (1024)
  const int tx = threadIdx.x & 63, ty = threadIdx.x >> 6;
  for (int uu = ty; uu < 64; uu += 4) {
    int gi = (u0 + uu) * 9216 + i0 + tx;
    float wv = gload(fc1w, gi, isb);
    float mv = gload(mraw, gi, isb);
    tile[uu][tx] = (mv < 0.5f) ? wv : 0.0f;
  }
  __syncthreads();
  for (int ii = ty; ii < 64; ii += 4)
    WtF[(i0 + ii) * 1024 + u0 + tx] = tile[tx][ii];
}

// ---------------- k_conv: f32 conv5x5 (Eigen kh-fastest order), bias, maxpool2, kwinners ----------------
// Thread owns (channel, half, 6 pooled rows): sliding 6-row register window.
// Emits winners SORTED by flat index (per-thread ranges contiguous ascending).
__global__ __launch_bounds__(256) void k_conv(const void* __restrict__ x,
                                              const void* __restrict__ c1w_g,
                                              const void* __restrict__ c1b_g,
                                              const void* __restrict__ duty_g,
                                              int2* __restrict__ wpair,
                                              int* __restrict__ wcnt,
                                              const int* __restrict__ flag) {
  __shared__ __align__(16) float img[784];
  __shared__ float cw[1600];
  __shared__ float cb[64], bcs[64];
  __shared__ __align__(16) float pooled[9216];
  __shared__ unsigned hist[256];
  __shared__ unsigned wtot[4];
  __shared__ unsigned selb, selk;
  const int tid = threadIdx.x;
  const int b = blockIdx.x;
  const int isb = *flag;
  const int lane = tid & 63;
  const int wv_id = tid >> 6;

  for (int i = tid; i < 784; i += 256) img[i] = gload(x, b * 784 + i, isb);
  for (int i = tid; i < 1600; i += 256) cw[i] = gload(c1w_g, i, isb);
  if (tid < 64) {
    cb[tid] = gload(c1b_g, tid, isb);
    float arg = (float)(400.0 / 9216.0) - gload(duty_g, tid, isb);
    bcs[tid] = (float)exp((double)arg);
  }
  __syncthreads();

  // mapping: c = tid>>2 (64), half = tid&1 (2), pg = (tid>>1)&1 (2) -> ph0 = pg*6
  {
    const int c = tid >> 2;
    const int half = tid & 1;
    const int ph0 = ((tid >> 1) & 1) * 6;
    float w[25];
#pragma unroll
    for (int i = 0; i < 25; ++i) w[i] = cw[c * 25 + i];
    const float bias = cb[c];
    float R[6][16];
#pragma unroll
    for (int r = 0; r < 6; ++r) {
      int ir = 2 * ph0 + r;
#pragma unroll
      for (int q = 0; q < 4; ++q)
        ((float4*)&R[r][0])[q] = ((const float4*)img)[ir * 7 + half * 3 + q];
    }
#pragma unroll
    for (int i = 0; i < 6; ++i) {
      const int ph = ph0 + i;
      float a0[12], a1[12];
#pragma unroll
      for (int j = 0; j < 12; ++j) { a0[j] = 0.f; a1[j] = 0.f; }
      // single sequential fmaf chain per conv cell, k = kw*5 + kh order
      // (kh fastest -- Eigen patch linearization) => bit-exact vs reference
#pragma unroll
      for (int kj = 0; kj < 5; ++kj) {       // kw OUTER
#pragma unroll
        for (int kr = 0; kr < 5; ++kr) {     // kh INNER (fastest)
          float wk = w[kr * 5 + kj];
          const float* r0 = &R[(2 * i + kr) % 6][0];
          const float* r1 = &R[(2 * i + kr + 1) % 6][0];
#pragma unroll
          for (int j = 0; j < 12; ++j) {
            a0[j] = fmaf(r0[j + kj], wk, a0[j]);
            a1[j] = fmaf(r1[j + kj], wk, a1[j]);
          }
        }
      }
      int obase = c * 144 + ph * 12 + half * 6;
#pragma unroll
      for (int q = 0; q < 6; ++q) {
        float m = fmaxf(fmaxf(a0[2 * q], a0[2 * q + 1]),
                        fmaxf(a1[2 * q], a1[2 * q + 1]));
        pooled[obase + q] = m + bias;
      }
      if (i < 5) {  // slide: load img rows 2*ph+6, 2*ph+7 over the two oldest
        int ir0 = 2 * ph + 6, ir1 = 2 * ph + 7;
        float* d0 = &R[(2 * i) % 6][0];
        float* d1 = &R[(2 * i + 1) % 6][0];
#pragma unroll
        for (int q = 0; q < 4; ++q) {
          ((float4*)d0)[q] = ((const float4*)img)[ir0 * 7 + half * 3 + q];
          ((float4*)d1)[q] = ((const float4*)img)[ir1 * 7 + half * 3 + q];
        }
      }
    }
  }
  __syncthreads();

  // compute this thread's 36 select keys ONCE into registers
  // (boost channel index o/144 is constant per thread: tid>>2)
  unsigned keys[36];
  {
    const float bcf = bcs[tid >> 2];
#pragma unroll
    for (int e4 = 0; e4 < 9; ++e4) {
      float4 pv = ((float4*)pooled)[tid * 9 + e4];
      keys[4 * e4 + 0] = tokey(pv.x * bcf);
      keys[4 * e4 + 1] = tokey(pv.y * bcf);
      keys[4 * e4 + 2] = tokey(pv.z * bcf);
      keys[4 * e4 + 3] = tokey(pv.w * bcf);
    }
  }

  // radix-select the 400th-largest key; shfl-based suffix scan (4 barriers/pass)
  unsigned kfix = 0;
  unsigned kk = 400;
  for (int pass = 3; pass >= 0; --pass) {
    const int shift = pass * 8;
    const unsigned himask = (pass == 3) ? 0u : (0xFFFFFFFFu << (shift + 8));
    hist[tid] = 0;
    __syncthreads();
#pragma unroll
    for (int e = 0; e < 36; ++e) {
      unsigned key = keys[e];
      if (((key ^ kfix) & himask) == 0)
        atomicAdd(&hist[(key >> shift) & 255u], 1u);
    }
    __syncthreads();
    unsigned own = hist[tid];
    unsigned v = own;
#pragma unroll
    for (int off = 1; off < 64; off <<= 1) {
      unsigned y = __shfl_down(v, off, 64);
      if (lane + off < 64) v += y;
    }
    if (lane == 0) wtot[wv_id] = v;
    __syncthreads();
#pragma unroll
    for (int w2 = 0; w2 < 4; ++w2)
      if (w2 > wv_id) v += wtot[w2];
    unsigned snext = v - own;
    if (v >= kk && snext < kk) {
      selb = (unsigned)tid;
      selk = kk - snext;
    }
    __syncthreads();
    kfix |= selb << shift;
    kk = selk;
    __syncthreads();
  }

  // sorted compaction: per-thread count -> shfl prefix scan -> ordered write.
  // keep ALL with key >= kfix (== boosted >= thr bitwise, ties kept like ref)
  unsigned mycnt = 0;
#pragma unroll
  for (int e = 0; e < 36; ++e) mycnt += (keys[e] >= kfix) ? 1u : 0u;
  unsigned px = mycnt;
#pragma unroll
  for (int off = 1; off < 64; off <<= 1) {
    unsigned y = __shfl_up(px, off, 64);
    if (lane >= off) px += y;
  }
  if (lane == 63) wtot[wv_id] = px;
  __syncthreads();
  unsigned base = 0;
#pragma unroll
  for (int w2 = 0; w2 < 4; ++w2)
    if (w2 < wv_id) base += wtot[w2];
  int pos = (int)(base + px - mycnt);  // exclusive prefix
  for (int e = 0; e < 36; ++e) {
    if (keys[e] >= kfix) {
      int o = tid * 36 + e;
      if (pos < 512) wpair[b * 512 + pos] = make_int2(__float_as_int(pooled[o]), o);
      ++pos;
    }
  }
  if (tid == 0) {
    unsigned tot = wtot[0] + wtot[1] + wtot[2] + wtot[3];
    wcnt[b] = (int)(tot < 512u ? tot : 512u);
  }
}

// ---------------- k_fc1: XCD-sliced sparse fc1 gather, scalarized winner stream ----------------
// slice = blockIdx.x & 7 -> round-robin across 8 XCDs; each XCD's L2 holds its
// 128-unit column slice of WtF (4.7 MB). One wave per block; thread owns 2 units.
// Winner index scalarized via readfirstlane -> scalar addr math, SGPR-base load.
// Single f32 fmaf chain per unit ascending-k => bit-identical h.
__global__ __launch_bounds__(64) void k_fc1(const float* __restrict__ WtF,
                                            const int2* __restrict__ wpair,
                                            const int* __restrict__ wcnt,
                                            const void* __restrict__ fc1b,
                                            float* __restrict__ h,
                                            const int* __restrict__ flag) {
  const int tid = threadIdx.x;       // 0..63
  const int img = blockIdx.x >> 3;
  const int slice = blockIdx.x & 7;
  const int isb = *flag;
  const int cnt = wcnt[img];
  const int u = (slice << 7) + 2 * tid;
  const float* __restrict__ W = WtF + u;
  const int2* __restrict__ wp = wpair + img * 512;
  float acc0 = 0.f, acc1 = 0.f;
  for (int w = 0; w < cnt; ++w) {
    int2 p = wp[w];  // block-uniform
    int idx = __builtin_amdgcn_readfirstlane(p.y);
    float v = __int_as_float(__builtin_amdgcn_readfirstlane(p.x));
    float2 wv2 = *(const float2*)(W + (size_t)idx * 1024);
    acc0 = fmaf(v, wv2.x, acc0);
    acc1 = fmaf(v, wv2.y, acc1);
  }
  float2 hb;
  hb.x = acc0 + gload(fc1b, u, isb);
  hb.y = acc1 + gload(fc1b, u + 1, isb);
  *(float2*)(h + img * 1024 + u) = hb;
}

// ---------------- k_sel: kwinners(k=100, >=thr) + f64 fc2 + log_softmax ----------------
__global__ __launch_bounds__(256) void k_sel(const float* __restrict__ h,
                                             const void* __restrict__ dutyfc,
                                             const void* __restrict__ fc2w,
                                             const void* __restrict__ fc2b,
                                             void* __restrict__ out,
                                             const int* __restrict__ flag) {
  __shared__ unsigned hist[256];
  __shared__ unsigned selb, selk;
  __shared__ double lg[10];
  __shared__ double mred[2];
  const int tid = threadIdx.x;
  const int row = blockIdx.x;
  const int isb = *flag;
  if (tid < 10) lg[tid] = (double)gload(fc2b, tid, isb);
  __syncthreads();

  const int u0 = 2 * tid, u1 = 2 * tid + 1, u2 = 512 + 2 * tid, u3 = 513 + 2 * tid;
  float2 hlo = ((const float2*)(h + row * 1024))[tid];
  float2 hhi = ((const float2*)(h + row * 1024 + 512))[tid];
  float h0 = hlo.x, h1 = hlo.y, h2 = hhi.x, h3 = hhi.y;
  float bf0 = (float)exp((double)(0.09765625f - gload(dutyfc, u0, isb)));
  float bf1 = (float)exp((double)(0.09765625f - gload(dutyfc, u1, isb)));
  float bf2 = (float)exp((double)(0.09765625f - gload(dutyfc, u2, isb)));
  float bf3 = (float)exp((double)(0.09765625f - gload(dutyfc, u3, isb)));
  unsigned k0 = tokey(h0 * bf0);
  unsigned k1 = tokey(h1 * bf1);
  unsigned k2 = tokey(h2 * bf2);
  unsigned k3 = tokey(h3 * bf3);

  // radix-select: 100th largest of 1024 f32 keys
  unsigned kfix = 0;
  int kk = 100;
  for (int pass = 3; pass >= 0; --pass) {
    const int shift = pass * 8;
    const unsigned himask = (pass == 3) ? 0u : (0xFFFFFFFFu << (shift + 8));
    hist[tid] = 0;
    __syncthreads();
    if (((k0 ^ kfix) & himask) == 0) atomicAdd(&hist[(k0 >> shift) & 255u], 1u);
    if (((k1 ^ kfix) & himask) == 0) atomicAdd(&hist[(k1 >> shift) & 255u], 1u);
    if (((k2 ^ kfix) & himask) == 0) atomicAdd(&hist[(k2 >> shift) & 255u], 1u);
    if (((k3 ^ kfix) & himask) == 0) atomicAdd(&hist[(k3 >> shift) & 255u], 1u);
    __syncthreads();
    unsigned v = hist[tid];
    for (int offs = 1; offs < 256; offs <<= 1) {
      unsigned other = (tid + offs < 256) ? hist[tid + offs] : 0u;
      __syncthreads();
      v += other;
      hist[tid] = v;
      __syncthreads();
    }
    unsigned snext = (tid < 255) ? hist[tid + 1] : 0u;
    if (v >= (unsigned)kk && snext < (unsigned)kk) {
      selb = (unsigned)tid;
      selk = (unsigned)(kk - (int)snext);
    }
    __syncthreads();
    kfix |= selb << shift;
    kk = (int)selk;
    __syncthreads();
  }
  bool kp0 = k0 >= kfix, kp1 = k1 >= kfix, kp2 = k2 >= kfix, kp3 = k3 >= kfix;

  // fc2 on kept units only (f64), wave-reduce, LDS-atomic combine
  double part[10];
#pragma unroll
  for (int c = 0; c < 10; ++c) part[c] = 0.0;
  if (kp0) {
#pragma unroll
    for (int c = 0; c < 10; ++c) part[c] = fma((double)h0, (double)gload(fc2w, c * 1024 + u0, isb), part[c]);
  }
  if (kp1) {
#pragma unroll
    for (int c = 0; c < 10; ++c) part[c] = fma((double)h1, (double)gload(fc2w, c * 1024 + u1, isb), part[c]);
  }
  if (kp2) {
#pragma unroll
    for (int c = 0; c < 10; ++c) part[c] = fma((double)h2, (double)gload(fc2w, c * 1024 + u2, isb), part[c]);
  }
  if (kp3) {
#pragma unroll
    for (int c = 0; c < 10; ++c) part[c] = fma((double)h3, (double)gload(fc2w, c * 1024 + u3, isb), part[c]);
  }
#pragma unroll
  for (int c = 0; c < 10; ++c) {
    double p = part[c];
    for (int off = 32; off > 0; off >>= 1) p += __shfl_xor(p, off);
    if ((tid & 63) == 0) atomicAdd(&lg[c], p);
  }
  __syncthreads();
  if (tid == 0) {
    double m = lg[0];
#pragma unroll
    for (int c = 1; c < 10; ++c) m = lg[c] > m ? lg[c] : m;
    double sum = 0.0;
#pragma unroll
    for (int c = 0; c < 10; ++c) sum += exp(lg[c] - m);
    mred[0] = m;
    mred[1] = log(sum);
  }
  __syncthreads();
  if (tid < 10) {
    double o = lg[tid] - mred[0] - mred[1];
    if (isb)
      ((unsigned short*)out)[row * 10 + tid] = f2b((float)o);
    else
      ((float*)out)[row * 10 + tid] = (float)o;
  }
}

// ---------------- launch ----------------
extern "C" void kernel_launch(void* const* d_in, const int* in_sizes, int n_in,
                              void* d_out, int out_size, void* d_ws, size_t ws_size,
                              hipStream_t stream) {
  // ws layout (bytes):
  //   WtF   : 9216*1024*4 = 37,748,736  @ 0
  //   wpair : 4096*512*8  = 16,777,216  @ 37,748,736
  //   wcnt  : 4096*4      =     16,384  @ 54,525,952
  //   h     : 4096*1024*4 = 16,777,216  @ 54,542,336
  //   flag  : 4                         @ 71,319,552
  char* ws = (char*)d_ws;
  float* WtF = (float*)ws;
  int2* wpair = (int2*)(ws + 37748736);
  int* wcnt = (int*)(ws + 54525952);
  float* h = (float*)(ws + 54542336);
  int* flag = (int*)(ws + 71319552);

  k_detect<<<1, 64, 0, stream>>>(d_in[0], flag);
  k_prep<<<dim3(144, 16), 256, 0, stream>>>(d_in[4], d_in[5], WtF, flag);
  k_conv<<<4096, 256, 0, stream>>>(d_in[0], d_in[1], d_in[2], d_in[3],
                                   wpair, wcnt, flag);
  k_fc1<<<4096 * 8, 64, 0, stream>>>(WtF, wpair, wcnt, d_in[6], h, flag);
  k_sel<<<4096, 256, 0, stream>>>(h, d_in[7], d_in[8], d_in[9], d_out, flag);
}

// Round 8
// 738.333 us; speedup vs baseline: 1.1965x; 1.1965x over previous
//
#include <hip/hip_runtime.h>

// ---------------- dtype helpers ----------------
__device__ __forceinline__ float b2f(unsigned short u) {
  return __uint_as_float(((unsigned)u) << 16);
}
__device__ __forceinline__ unsigned short f2b(float f) {
  unsigned u = __float_as_uint(f);
  return (unsigned short)((u + 0x7FFFu + ((u >> 16) & 1u)) >> 16);
}
// load element i of a tensor that is bf16 (isb=1) or fp32 (isb=0)
__device__ __forceinline__ float gload(const void* p, int i, int isb) {
  return isb ? b2f(((const unsigned short*)p)[i]) : ((const float*)p)[i];
}
// monotone bijection float -> uint32 (order-preserving incl. negatives)
__device__ __forceinline__ unsigned tokey(float f) {
  unsigned u = __float_as_uint(f);
  return u ^ (unsigned)(((int)u >> 31) | 0x80000000u);
}

// ---------------- dtype detector (dataset proven fp32; kept for safety) ----------------
__global__ void k_detect(const void* x, int* flag) {
  int tid = threadIdx.x;  // 1 wave
  unsigned short u = ((const unsigned short*)x)[2 * tid];
  int e = (u >> 7) & 0xFF;
  bool sane = (e >= 100 && e <= 140);
  unsigned long long m = __ballot(sane);
  if (tid == 0) *flag = (__popcll(m) >= 40) ? 1 : 0;
}

// ---------------- k_prep: WtF[i][u] = fc1_w[u][i] * (mask<0.5), f32 transposed ----------------
__global__ __launch_bounds__(256) void k_prep(const void* __restrict__ fc1w,
                                              const void* __restrict__ mraw,
                                              float* __restrict__ WtF,
                                              const int* __restrict__ flag) {
  __shared__ float tile[64][65];
  const int isb = *flag;
  const int i0 = blockIdx.x * 64;  // K index (9216)
  const int u0 = blockIdx.y * 64;  // unit index (1024)
  const int tx = threadIdx.x & 63, ty = threadIdx.x >> 6;
  for (int uu = ty; uu < 64; uu += 4) {
    int gi = (u0 + uu) * 9216 + i0 + tx;
    float wv = gload(fc1w, gi, isb);
    float mv = gload(mraw, gi, isb);
    tile[uu][tx] = (mv < 0.5f) ? wv : 0.0f;
  }
  __syncthreads();
  for (int ii = ty; ii < 64; ii += 4)
    WtF[(i0 + ii) * 1024 + u0 + tx] = tile[tx][ii];
}

// ---------------- k_conv: f32 conv5x5 (Eigen kh-fastest order), bias, maxpool2, kwinners ----------------
// Thread owns (channel, half, 6 pooled rows): sliding 6-row register window.
// Emits winners SORTED by flat index; wpair.y holds the PREMULTIPLIED byte
// offset (o << 12) of the WtF row for k_fc1's addressing.
__global__ __launch_bounds__(256) void k_conv(const void* __restrict__ x,
                                              const void* __restrict__ c1w_g,
                                              const void* __restrict__ c1b_g,
                                              const void* __restrict__ duty_g,
                                              int2* __restrict__ wpair,
                                              int* __restrict__ wcnt,
                                              const int* __restrict__ flag) {
  __shared__ __align__(16) float img[784];
  __shared__ float cw[1600];
  __shared__ float cb[64], bcs[64];
  __shared__ __align__(16) float pooled[9216];
  __shared__ unsigned hist[256];
  __shared__ unsigned wtot[4];
  __shared__ unsigned selb, selk;
  const int tid = threadIdx.x;
  const int b = blockIdx.x;
  const int isb = *flag;
  const int lane = tid & 63;
  const int wv_id = tid >> 6;

  for (int i = tid; i < 784; i += 256) img[i] = gload(x, b * 784 + i, isb);
  for (int i = tid; i < 1600; i += 256) cw[i] = gload(c1w_g, i, isb);
  if (tid < 64) {
    cb[tid] = gload(c1b_g, tid, isb);
    float arg = (float)(400.0 / 9216.0) - gload(duty_g, tid, isb);
    bcs[tid] = (float)exp((double)arg);
  }
  __syncthreads();

  // mapping: c = tid>>2 (64), half = tid&1 (2), pg = (tid>>1)&1 (2) -> ph0 = pg*6
  {
    const int c = tid >> 2;
    const int half = tid & 1;
    const int ph0 = ((tid >> 1) & 1) * 6;
    float w[25];
#pragma unroll
    for (int i = 0; i < 25; ++i) w[i] = cw[c * 25 + i];
    const float bias = cb[c];
    float R[6][16];
#pragma unroll
    for (int r = 0; r < 6; ++r) {
      int ir = 2 * ph0 + r;
#pragma unroll
      for (int q = 0; q < 4; ++q)
        ((float4*)&R[r][0])[q] = ((const float4*)img)[ir * 7 + half * 3 + q];
    }
#pragma unroll
    for (int i = 0; i < 6; ++i) {
      const int ph = ph0 + i;
      float a0[12], a1[12];
#pragma unroll
      for (int j = 0; j < 12; ++j) { a0[j] = 0.f; a1[j] = 0.f; }
      // single sequential fmaf chain per conv cell, k = kw*5 + kh order
      // (kh fastest -- Eigen patch linearization) => bit-exact vs reference
#pragma unroll
      for (int kj = 0; kj < 5; ++kj) {       // kw OUTER
#pragma unroll
        for (int kr = 0; kr < 5; ++kr) {     // kh INNER (fastest)
          float wk = w[kr * 5 + kj];
          const float* r0 = &R[(2 * i + kr) % 6][0];
          const float* r1 = &R[(2 * i + kr + 1) % 6][0];
#pragma unroll
          for (int j = 0; j < 12; ++j) {
            a0[j] = fmaf(r0[j + kj], wk, a0[j]);
            a1[j] = fmaf(r1[j + kj], wk, a1[j]);
          }
        }
      }
      int obase = c * 144 + ph * 12 + half * 6;
#pragma unroll
      for (int q = 0; q < 6; ++q) {
        float m = fmaxf(fmaxf(a0[2 * q], a0[2 * q + 1]),
                        fmaxf(a1[2 * q], a1[2 * q + 1]));
        pooled[obase + q] = m + bias;
      }
      if (i < 5) {  // slide: load img rows 2*ph+6, 2*ph+7 over the two oldest
        int ir0 = 2 * ph + 6, ir1 = 2 * ph + 7;
        float* d0 = &R[(2 * i) % 6][0];
        float* d1 = &R[(2 * i + 1) % 6][0];
#pragma unroll
        for (int q = 0; q < 4; ++q) {
          ((float4*)d0)[q] = ((const float4*)img)[ir0 * 7 + half * 3 + q];
          ((float4*)d1)[q] = ((const float4*)img)[ir1 * 7 + half * 3 + q];
        }
      }
    }
  }
  __syncthreads();

  // compute this thread's 36 select keys ONCE into registers
  // (boost channel index o/144 is constant per thread: tid>>2)
  unsigned keys[36];
  {
    const float bcf = bcs[tid >> 2];
#pragma unroll
    for (int e4 = 0; e4 < 9; ++e4) {
      float4 pv = ((float4*)pooled)[tid * 9 + e4];
      keys[4 * e4 + 0] = tokey(pv.x * bcf);
      keys[4 * e4 + 1] = tokey(pv.y * bcf);
      keys[4 * e4 + 2] = tokey(pv.z * bcf);
      keys[4 * e4 + 3] = tokey(pv.w * bcf);
    }
  }

  // radix-select the 400th-largest key; shfl-based suffix scan (4 barriers/pass)
  unsigned kfix = 0;
  unsigned kk = 400;
  for (int pass = 3; pass >= 0; --pass) {
    const int shift = pass * 8;
    const unsigned himask = (pass == 3) ? 0u : (0xFFFFFFFFu << (shift + 8));
    hist[tid] = 0;
    __syncthreads();
#pragma unroll
    for (int e = 0; e < 36; ++e) {
      unsigned key = keys[e];
      if (((key ^ kfix) & himask) == 0)
        atomicAdd(&hist[(key >> shift) & 255u], 1u);
    }
    __syncthreads();
    unsigned own = hist[tid];
    unsigned v = own;
#pragma unroll
    for (int off = 1; off < 64; off <<= 1) {
      unsigned y = __shfl_down(v, off, 64);
      if (lane + off < 64) v += y;
    }
    if (lane == 0) wtot[wv_id] = v;
    __syncthreads();
#pragma unroll
    for (int w2 = 0; w2 < 4; ++w2)
      if (w2 > wv_id) v += wtot[w2];
    unsigned snext = v - own;
    if (v >= kk && snext < kk) {
      selb = (unsigned)tid;
      selk = kk - snext;
    }
    __syncthreads();
    kfix |= selb << shift;
    kk = selk;
    __syncthreads();
  }

  // sorted compaction: per-thread count -> shfl prefix scan -> ordered write.
  // keep ALL with key >= kfix (== boosted >= thr bitwise, ties kept like ref)
  unsigned mycnt = 0;
#pragma unroll
  for (int e = 0; e < 36; ++e) mycnt += (keys[e] >= kfix) ? 1u : 0u;
  unsigned px = mycnt;
#pragma unroll
  for (int off = 1; off < 64; off <<= 1) {
    unsigned y = __shfl_up(px, off, 64);
    if (lane >= off) px += y;
  }
  if (lane == 63) wtot[wv_id] = px;
  __syncthreads();
  unsigned base = 0;
#pragma unroll
  for (int w2 = 0; w2 < 4; ++w2)
    if (w2 < wv_id) base += wtot[w2];
  int pos = (int)(base + px - mycnt);  // exclusive prefix
  for (int e = 0; e < 36; ++e) {
    if (keys[e] >= kfix) {
      int o = tid * 36 + e;
      if (pos < 512)
        wpair[b * 512 + pos] = make_int2(__float_as_int(pooled[o]), o << 12);
      ++pos;
    }
  }
  if (tid == 0) {
    unsigned tot = wtot[0] + wtot[1] + wtot[2] + wtot[3];
    wcnt[b] = (int)(tot < 512u ? tot : 512u);
  }
}

// ---------------- k_fc1: XCD-sliced sparse fc1 gather ----------------
// slice = blockIdx.x & 7 -> consecutive blocks round-robin across the 8 XCDs,
// so each XCD's L2 only sees its 128-unit column slice of WtF (4.7 MB ~ L2).
// 64 threads/block; thread owns 2 units (float2 load, 512 B/wave-instr).
// Winner list staged in LDS; inner loop per winner: broadcast ds_read_b64
// (val + premultiplied row byte-offset), one v_add, one global_load_dwordx2,
// two fmaf. Single f32 fmaf chain per unit ascending-k => bit-identical h.
__global__ __launch_bounds__(64) void k_fc1(const float* __restrict__ WtF,
                                            const int2* __restrict__ wpair,
                                            const int* __restrict__ wcnt,
                                            const void* __restrict__ fc1b,
                                            float* __restrict__ h,
                                            const int* __restrict__ flag) {
  __shared__ int2 wl[512];
  const int tid = threadIdx.x;  // 0..63
  const int img = blockIdx.x >> 3;
  const int slice = blockIdx.x & 7;
  const int isb = *flag;
  const int cnt = wcnt[img];
  const int2* __restrict__ wp = wpair + img * 512;
  for (int i = tid; i < cnt; i += 64) wl[i] = wp[i];
  __syncthreads();
  const int u = (slice << 7) + 2 * tid;
  const unsigned ub = (unsigned)u * 4u;  // lane column byte offset
  const char* __restrict__ Wb = (const char*)WtF;
  float acc0 = 0.f, acc1 = 0.f;
#pragma unroll 4
  for (int w = 0; w < cnt; ++w) {
    int2 p = wl[w];  // broadcast LDS read (same addr all lanes)
    float v = __int_as_float(p.x);
    float2 wv2 = *(const float2*)(Wb + ((unsigned)p.y + ub));
    acc0 = fmaf(v, wv2.x, acc0);
    acc1 = fmaf(v, wv2.y, acc1);
  }
  float2 hb;
  hb.x = acc0 + gload(fc1b, u, isb);
  hb.y = acc1 + gload(fc1b, u + 1, isb);
  *(float2*)(h + img * 1024 + u) = hb;
}

// ---------------- k_sel: kwinners(k=100, >=thr) + f64 fc2 + log_softmax ----------------
__global__ __launch_bounds__(256) void k_sel(const float* __restrict__ h,
                                             const void* __restrict__ dutyfc,
                                             const void* __restrict__ fc2w,
                                             const void* __restrict__ fc2b,
                                             void* __restrict__ out,
                                             const int* __restrict__ flag) {
  __shared__ unsigned hist[256];
  __shared__ unsigned selb, selk;
  __shared__ double lg[10];
  __shared__ double mred[2];
  const int tid = threadIdx.x;
  const int row = blockIdx.x;
  const int isb = *flag;
  if (tid < 10) lg[tid] = (double)gload(fc2b, tid, isb);
  __syncthreads();

  const int u0 = 2 * tid, u1 = 2 * tid + 1, u2 = 512 + 2 * tid, u3 = 513 + 2 * tid;
  float2 hlo = ((const float2*)(h + row * 1024))[tid];
  float2 hhi = ((const float2*)(h + row * 1024 + 512))[tid];
  float h0 = hlo.x, h1 = hlo.y, h2 = hhi.x, h3 = hhi.y;
  float bf0 = (float)exp((double)(0.09765625f - gload(dutyfc, u0, isb)));
  float bf1 = (float)exp((double)(0.09765625f - gload(dutyfc, u1, isb)));
  float bf2 = (float)exp((double)(0.09765625f - gload(dutyfc, u2, isb)));
  float bf3 = (float)exp((double)(0.09765625f - gload(dutyfc, u3, isb)));
  unsigned k0 = tokey(h0 * bf0);
  unsigned k1 = tokey(h1 * bf1);
  unsigned k2 = tokey(h2 * bf2);
  unsigned k3 = tokey(h3 * bf3);

  // radix-select: 100th largest of 1024 f32 keys
  unsigned kfix = 0;
  int kk = 100;
  for (int pass = 3; pass >= 0; --pass) {
    const int shift = pass * 8;
    const unsigned himask = (pass == 3) ? 0u : (0xFFFFFFFFu << (shift + 8));
    hist[tid] = 0;
    __syncthreads();
    if (((k0 ^ kfix) & himask) == 0) atomicAdd(&hist[(k0 >> shift) & 255u], 1u);
    if (((k1 ^ kfix) & himask) == 0) atomicAdd(&hist[(k1 >> shift) & 255u], 1u);
    if (((k2 ^ kfix) & himask) == 0) atomicAdd(&hist[(k2 >> shift) & 255u], 1u);
    if (((k3 ^ kfix) & himask) == 0) atomicAdd(&hist[(k3 >> shift) & 255u], 1u);
    __syncthreads();
    unsigned v = hist[tid];
    for (int offs = 1; offs < 256; offs <<= 1) {
      unsigned other = (tid + offs < 256) ? hist[tid + offs] : 0u;
      __syncthreads();
      v += other;
      hist[tid] = v;
      __syncthreads();
    }
    unsigned snext = (tid < 255) ? hist[tid + 1] : 0u;
    if (v >= (unsigned)kk && snext < (unsigned)kk) {
      selb = (unsigned)tid;
      selk = (unsigned)(kk - (int)snext);
    }
    __syncthreads();
    kfix |= selb << shift;
    kk = (int)selk;
    __syncthreads();
  }
  bool kp0 = k0 >= kfix, kp1 = k1 >= kfix, kp2 = k2 >= kfix, kp3 = k3 >= kfix;

  // fc2 on kept units only (f64), wave-reduce, LDS-atomic combine
  double part[10];
#pragma unroll
  for (int c = 0; c < 10; ++c) part[c] = 0.0;
  if (kp0) {
#pragma unroll
    for (int c = 0; c < 10; ++c) part[c] = fma((double)h0, (double)gload(fc2w, c * 1024 + u0, isb), part[c]);
  }
  if (kp1) {
#pragma unroll
    for (int c = 0; c < 10; ++c) part[c] = fma((double)h1, (double)gload(fc2w, c * 1024 + u1, isb), part[c]);
  }
  if (kp2) {
#pragma unroll
    for (int c = 0; c < 10; ++c) part[c] = fma((double)h2, (double)gload(fc2w, c * 1024 + u2, isb), part[c]);
  }
  if (kp3) {
#pragma unroll
    for (int c = 0; c < 10; ++c) part[c] = fma((double)h3, (double)gload(fc2w, c * 1024 + u3, isb), part[c]);
  }
#pragma unroll
  for (int c = 0; c < 10; ++c) {
    double p = part[c];
    for (int off = 32; off > 0; off >>= 1) p += __shfl_xor(p, off);
    if ((tid & 63) == 0) atomicAdd(&lg[c], p);
  }
  __syncthreads();
  if (tid == 0) {
    double m = lg[0];
#pragma unroll
    for (int c = 1; c < 10; ++c) m = lg[c] > m ? lg[c] : m;
    double sum = 0.0;
#pragma unroll
    for (int c = 0; c < 10; ++c) sum += exp(lg[c] - m);
    mred[0] = m;
    mred[1] = log(sum);
  }
  __syncthreads();
  if (tid < 10) {
    double o = lg[tid] - mred[0] - mred[1];
    if (isb)
      ((unsigned short*)out)[row * 10 + tid] = f2b((float)o);
    else
      ((float*)out)[row * 10 + tid] = (float)o;
  }
}

// ---------------- launch ----------------
extern "C" void kernel_launch(void* const* d_in, const int* in_sizes, int n_in,
                              void* d_out, int out_size, void* d_ws, size_t ws_size,
                              hipStream_t stream) {
  // ws layout (bytes):
  //   WtF   : 9216*1024*4 = 37,748,736  @ 0
  //   wpair : 4096*512*8  = 16,777,216  @ 37,748,736
  //   wcnt  : 4096*4      =     16,384  @ 54,525,952
  //   h     : 4096*1024*4 = 16,777,216  @ 54,542,336
  //   flag  : 4                         @ 71,319,552
  char* ws = (char*)d_ws;
  float* WtF = (float*)ws;
  int2* wpair = (int2*)(ws + 37748736);
  int* wcnt = (int*)(ws + 54525952);
  float* h = (float*)(ws + 54542336);
  int* flag = (int*)(ws + 71319552);

  k_detect<<<1, 64, 0, stream>>>(d_in[0], flag);
  k_prep<<<dim3(144, 16), 256, 0, stream>>>(d_in[4], d_in[5], WtF, flag);
  k_conv<<<4096, 256, 0, stream>>>(d_in[0], d_in[1], d_in[2], d_in[3],
                                   wpair, wcnt, flag);
  k_fc1<<<4096 * 8, 64, 0, stream>>>(WtF, wpair, wcnt, d_in[6], h, flag);
  k_sel<<<4096, 256, 0, stream>>>(h, d_in[7], d_in[8], d_in[9], d_out, flag);
}

// Round 9
// 624.499 us; speedup vs baseline: 1.4146x; 1.1823x over previous
//
#include <hip/hip_runtime.h>

// ---------------- dtype helpers ----------------
__device__ __forceinline__ float b2f(unsigned short u) {
  return __uint_as_float(((unsigned)u) << 16);
}
__device__ __forceinline__ unsigned short f2b(float f) {
  unsigned u = __float_as_uint(f);
  return (unsigned short)((u + 0x7FFFu + ((u >> 16) & 1u)) >> 16);
}
// load element i of a tensor that is bf16 (isb=1) or fp32 (isb=0)
__device__ __forceinline__ float gload(const void* p, int i, int isb) {
  return isb ? b2f(((const unsigned short*)p)[i]) : ((const float*)p)[i];
}
// monotone bijection float -> uint32 (order-preserving incl. negatives)
__device__ __forceinline__ unsigned tokey(float f) {
  unsigned u = __float_as_uint(f);
  return u ^ (unsigned)(((int)u >> 31) | 0x80000000u);
}

// ---------------- dtype detector (dataset proven fp32; kept for safety) ----------------
__global__ void k_detect(const void* x, int* flag) {
  int tid = threadIdx.x;  // 1 wave
  unsigned short u = ((const unsigned short*)x)[2 * tid];
  int e = (u >> 7) & 0xFF;
  bool sane = (e >= 100 && e <= 140);
  unsigned long long m = __ballot(sane);
  if (tid == 0) *flag = (__popcll(m) >= 40) ? 1 : 0;
}

// ---------------- k_prep: WtF[i][u] = fc1_w[u][i] * (mask<0.5), f32 transposed ----------------
__global__ __launch_bounds__(256) void k_prep(const void* __restrict__ fc1w,
                                              const void* __restrict__ mraw,
                                              float* __restrict__ WtF,
                                              const int* __restrict__ flag) {
  __shared__ float tile[64][65];
  const int isb = *flag;
  const int i0 = blockIdx.x * 64;  // K index (9216)
  const int u0 = blockIdx.y * 64;  // unit index (1024)
  const int tx = threadIdx.x & 63, ty = threadIdx.x >> 6;
  for (int uu = ty; uu < 64; uu += 4) {
    int gi = (u0 + uu) * 9216 + i0 + tx;
    float wv = gload(fc1w, gi, isb);
    float mv = gload(mraw, gi, isb);
    tile[uu][tx] = (mv < 0.5f) ? wv : 0.0f;
  }
  __syncthreads();
  for (int ii = ty; ii < 64; ii += 4)
    WtF[(i0 + ii) * 1024 + u0 + tx] = tile[tx][ii];
}

// ---------------- k_conv: f32 conv5x5 (Eigen kh-fastest order), bias, maxpool2, kwinners ----------------
// Thread owns (channel, half, 6 pooled rows): sliding 6-row register window.
// Radix histogram split 4-ways (per wave) to cut same-bin LDS atomic serialization.
// Emits winners SORTED by flat index; wpair.y = premultiplied WtF row byte offset (o<<12).
__global__ __launch_bounds__(256) void k_conv(const void* __restrict__ x,
                                              const void* __restrict__ c1w_g,
                                              const void* __restrict__ c1b_g,
                                              const void* __restrict__ duty_g,
                                              int2* __restrict__ wpair,
                                              int* __restrict__ wcnt,
                                              const int* __restrict__ flag) {
  __shared__ __align__(16) float img[784];
  __shared__ float cw[1600];
  __shared__ float cb[64], bcs[64];
  __shared__ __align__(16) float pooled[9216];
  __shared__ unsigned hist4[4][256];
  __shared__ unsigned wtot[4];
  __shared__ unsigned selb, selk;
  const int tid = threadIdx.x;
  const int b = blockIdx.x;
  const int isb = *flag;
  const int lane = tid & 63;
  const int wv_id = tid >> 6;

  for (int i = tid; i < 784; i += 256) img[i] = gload(x, b * 784 + i, isb);
  for (int i = tid; i < 1600; i += 256) cw[i] = gload(c1w_g, i, isb);
  if (tid < 64) {
    cb[tid] = gload(c1b_g, tid, isb);
    float arg = (float)(400.0 / 9216.0) - gload(duty_g, tid, isb);
    bcs[tid] = (float)exp((double)arg);
  }
  __syncthreads();

  // mapping: c = tid>>2 (64), half = tid&1 (2), pg = (tid>>1)&1 (2) -> ph0 = pg*6
  {
    const int c = tid >> 2;
    const int half = tid & 1;
    const int ph0 = ((tid >> 1) & 1) * 6;
    float w[25];
#pragma unroll
    for (int i = 0; i < 25; ++i) w[i] = cw[c * 25 + i];
    const float bias = cb[c];
    float R[6][16];
#pragma unroll
    for (int r = 0; r < 6; ++r) {
      int ir = 2 * ph0 + r;
#pragma unroll
      for (int q = 0; q < 4; ++q)
        ((float4*)&R[r][0])[q] = ((const float4*)img)[ir * 7 + half * 3 + q];
    }
#pragma unroll
    for (int i = 0; i < 6; ++i) {
      const int ph = ph0 + i;
      float a0[12], a1[12];
#pragma unroll
      for (int j = 0; j < 12; ++j) { a0[j] = 0.f; a1[j] = 0.f; }
      // single sequential fmaf chain per conv cell, k = kw*5 + kh order
      // (kh fastest -- Eigen patch linearization) => bit-exact vs reference
#pragma unroll
      for (int kj = 0; kj < 5; ++kj) {       // kw OUTER
#pragma unroll
        for (int kr = 0; kr < 5; ++kr) {     // kh INNER (fastest)
          float wk = w[kr * 5 + kj];
          const float* r0 = &R[(2 * i + kr) % 6][0];
          const float* r1 = &R[(2 * i + kr + 1) % 6][0];
#pragma unroll
          for (int j = 0; j < 12; ++j) {
            a0[j] = fmaf(r0[j + kj], wk, a0[j]);
            a1[j] = fmaf(r1[j + kj], wk, a1[j]);
          }
        }
      }
      int obase = c * 144 + ph * 12 + half * 6;
#pragma unroll
      for (int q = 0; q < 6; ++q) {
        float m = fmaxf(fmaxf(a0[2 * q], a0[2 * q + 1]),
                        fmaxf(a1[2 * q], a1[2 * q + 1]));
        pooled[obase + q] = m + bias;
      }
      if (i < 5) {  // slide: load img rows 2*ph+6, 2*ph+7 over the two oldest
        int ir0 = 2 * ph + 6, ir1 = 2 * ph + 7;
        float* d0 = &R[(2 * i) % 6][0];
        float* d1 = &R[(2 * i + 1) % 6][0];
#pragma unroll
        for (int q = 0; q < 4; ++q) {
          ((float4*)d0)[q] = ((const float4*)img)[ir0 * 7 + half * 3 + q];
          ((float4*)d1)[q] = ((const float4*)img)[ir1 * 7 + half * 3 + q];
        }
      }
    }
  }
  __syncthreads();

  // compute this thread's 36 select keys ONCE into registers
  // (boost channel index o/144 is constant per thread: tid>>2)
  unsigned keys[36];
  {
    const float bcf = bcs[tid >> 2];
#pragma unroll
    for (int e4 = 0; e4 < 9; ++e4) {
      float4 pv = ((float4*)pooled)[tid * 9 + e4];
      keys[4 * e4 + 0] = tokey(pv.x * bcf);
      keys[4 * e4 + 1] = tokey(pv.y * bcf);
      keys[4 * e4 + 2] = tokey(pv.z * bcf);
      keys[4 * e4 + 3] = tokey(pv.w * bcf);
    }
  }

  // radix-select the 400th-largest key; per-wave split histograms + shfl suffix scan
  unsigned kfix = 0;
  unsigned kk = 400;
  for (int pass = 3; pass >= 0; --pass) {
    const int shift = pass * 8;
    const unsigned himask = (pass == 3) ? 0u : (0xFFFFFFFFu << (shift + 8));
#pragma unroll
    for (int w2 = 0; w2 < 4; ++w2) hist4[w2][tid] = 0;
    __syncthreads();
    unsigned* myh = hist4[wv_id];
#pragma unroll
    for (int e = 0; e < 36; ++e) {
      unsigned key = keys[e];
      if (((key ^ kfix) & himask) == 0)
        atomicAdd(&myh[(key >> shift) & 255u], 1u);
    }
    __syncthreads();
    unsigned own = hist4[0][tid] + hist4[1][tid] + hist4[2][tid] + hist4[3][tid];
    unsigned v = own;
#pragma unroll
    for (int off = 1; off < 64; off <<= 1) {
      unsigned y = __shfl_down(v, off, 64);
      if (lane + off < 64) v += y;
    }
    if (lane == 0) wtot[wv_id] = v;
    __syncthreads();
#pragma unroll
    for (int w2 = 0; w2 < 4; ++w2)
      if (w2 > wv_id) v += wtot[w2];
    unsigned snext = v - own;
    if (v >= kk && snext < kk) {
      selb = (unsigned)tid;
      selk = kk - snext;
    }
    __syncthreads();
    kfix |= selb << shift;
    kk = selk;
    __syncthreads();
  }

  // sorted compaction: per-thread count -> shfl prefix scan -> ordered write.
  // keep ALL with key >= kfix (== boosted >= thr bitwise, ties kept like ref)
  unsigned mycnt = 0;
#pragma unroll
  for (int e = 0; e < 36; ++e) mycnt += (keys[e] >= kfix) ? 1u : 0u;
  unsigned px = mycnt;
#pragma unroll
  for (int off = 1; off < 64; off <<= 1) {
    unsigned y = __shfl_up(px, off, 64);
    if (lane >= off) px += y;
  }
  if (lane == 63) wtot[wv_id] = px;
  __syncthreads();
  unsigned base = 0;
#pragma unroll
  for (int w2 = 0; w2 < 4; ++w2)
    if (w2 < wv_id) base += wtot[w2];
  int pos = (int)(base + px - mycnt);  // exclusive prefix
  for (int e = 0; e < 36; ++e) {
    if (keys[e] >= kfix) {
      int o = tid * 36 + e;
      if (pos < 512)
        wpair[b * 512 + pos] = make_int2(__float_as_int(pooled[o]), o << 12);
      ++pos;
    }
  }
  if (tid == 0) {
    unsigned tot = wtot[0] + wtot[1] + wtot[2] + wtot[3];
    wcnt[b] = (int)(tot < 512u ? tot : 512u);
  }
}

// ---------------- k_fc1: XCD-sliced sparse fc1 gather ----------------
// slice = blockIdx.x & 7 -> consecutive blocks round-robin across the 8 XCDs,
// so each XCD's L2 only sees its 128-unit column slice of WtF (4.7 MB ~ L2).
// 128 threads/block (2 waves: r6's proven-fast residency shape; 64-thr blocks
// halved resident waves via the per-CU workgroup cap and went latency-bound).
// Thread owns ONE unit; per winner: broadcast ds_read_b64 (val + premultiplied
// row byte offset), one v_add, one global_load_dword, one fmaf.
// Single f32 fmaf chain per unit ascending-k => bit-identical h.
__global__ __launch_bounds__(128) void k_fc1(const float* __restrict__ WtF,
                                             const int2* __restrict__ wpair,
                                             const int* __restrict__ wcnt,
                                             const void* __restrict__ fc1b,
                                             float* __restrict__ h,
                                             const int* __restrict__ flag) {
  __shared__ int2 wl[512];
  const int tid = threadIdx.x;  // 0..127
  const int img = blockIdx.x >> 3;
  const int slice = blockIdx.x & 7;
  const int isb = *flag;
  const int cnt = wcnt[img];
  const int2* __restrict__ wp = wpair + img * 512;
  for (int i = tid; i < cnt; i += 128) wl[i] = wp[i];
  __syncthreads();
  const int u = (slice << 7) + tid;
  const unsigned ub = (unsigned)u * 4u;  // lane column byte offset
  const char* __restrict__ Wb = (const char*)WtF;
  float acc = 0.f;
#pragma unroll 8
  for (int w = 0; w < cnt; ++w) {
    int2 p = wl[w];  // broadcast LDS read (same addr all lanes)
    acc = fmaf(__int_as_float(p.x),
               *(const float*)(Wb + ((unsigned)p.y + ub)), acc);
  }
  h[img * 1024 + u] = acc + gload(fc1b, u, isb);
}

// ---------------- k_sel: kwinners(k=100, >=thr) + f64 fc2 + log_softmax ----------------
__global__ __launch_bounds__(256) void k_sel(const float* __restrict__ h,
                                             const void* __restrict__ dutyfc,
                                             const void* __restrict__ fc2w,
                                             const void* __restrict__ fc2b,
                                             void* __restrict__ out,
                                             const int* __restrict__ flag) {
  __shared__ unsigned hist[256];
  __shared__ unsigned selb, selk;
  __shared__ double lg[10];
  __shared__ double mred[2];
  const int tid = threadIdx.x;
  const int row = blockIdx.x;
  const int isb = *flag;
  if (tid < 10) lg[tid] = (double)gload(fc2b, tid, isb);
  __syncthreads();

  const int u0 = 2 * tid, u1 = 2 * tid + 1, u2 = 512 + 2 * tid, u3 = 513 + 2 * tid;
  float2 hlo = ((const float2*)(h + row * 1024))[tid];
  float2 hhi = ((const float2*)(h + row * 1024 + 512))[tid];
  float h0 = hlo.x, h1 = hlo.y, h2 = hhi.x, h3 = hhi.y;
  float bf0 = (float)exp((double)(0.09765625f - gload(dutyfc, u0, isb)));
  float bf1 = (float)exp((double)(0.09765625f - gload(dutyfc, u1, isb)));
  float bf2 = (float)exp((double)(0.09765625f - gload(dutyfc, u2, isb)));
  float bf3 = (float)exp((double)(0.09765625f - gload(dutyfc, u3, isb)));
  unsigned k0 = tokey(h0 * bf0);
  unsigned k1 = tokey(h1 * bf1);
  unsigned k2 = tokey(h2 * bf2);
  unsigned k3 = tokey(h3 * bf3);

  // radix-select: 100th largest of 1024 f32 keys
  unsigned kfix = 0;
  int kk = 100;
  for (int pass = 3; pass >= 0; --pass) {
    const int shift = pass * 8;
    const unsigned himask = (pass == 3) ? 0u : (0xFFFFFFFFu << (shift + 8));
    hist[tid] = 0;
    __syncthreads();
    if (((k0 ^ kfix) & himask) == 0) atomicAdd(&hist[(k0 >> shift) & 255u], 1u);
    if (((k1 ^ kfix) & himask) == 0) atomicAdd(&hist[(k1 >> shift) & 255u], 1u);
    if (((k2 ^ kfix) & himask) == 0) atomicAdd(&hist[(k2 >> shift) & 255u], 1u);
    if (((k3 ^ kfix) & himask) == 0) atomicAdd(&hist[(k3 >> shift) & 255u], 1u);
    __syncthreads();
    unsigned v = hist[tid];
    for (int offs = 1; offs < 256; offs <<= 1) {
      unsigned other = (tid + offs < 256) ? hist[tid + offs] : 0u;
      __syncthreads();
      v += other;
      hist[tid] = v;
      __syncthreads();
    }
    unsigned snext = (tid < 255) ? hist[tid + 1] : 0u;
    if (v >= (unsigned)kk && snext < (unsigned)kk) {
      selb = (unsigned)tid;
      selk = (unsigned)(kk - (int)snext);
    }
    __syncthreads();
    kfix |= selb << shift;
    kk = (int)selk;
    __syncthreads();
  }
  bool kp0 = k0 >= kfix, kp1 = k1 >= kfix, kp2 = k2 >= kfix, kp3 = k3 >= kfix;

  // fc2 on kept units only (f64), wave-reduce, LDS-atomic combine
  double part[10];
#pragma unroll
  for (int c = 0; c < 10; ++c) part[c] = 0.0;
  if (kp0) {
#pragma unroll
    for (int c = 0; c < 10; ++c) part[c] = fma((double)h0, (double)gload(fc2w, c * 1024 + u0, isb), part[c]);
  }
  if (kp1) {
#pragma unroll
    for (int c = 0; c < 10; ++c) part[c] = fma((double)h1, (double)gload(fc2w, c * 1024 + u1, isb), part[c]);
  }
  if (kp2) {
#pragma unroll
    for (int c = 0; c < 10; ++c) part[c] = fma((double)h2, (double)gload(fc2w, c * 1024 + u2, isb), part[c]);
  }
  if (kp3) {
#pragma unroll
    for (int c = 0; c < 10; ++c) part[c] = fma((double)h3, (double)gload(fc2w, c * 1024 + u3, isb), part[c]);
  }
#pragma unroll
  for (int c = 0; c < 10; ++c) {
    double p = part[c];
    for (int off = 32; off > 0; off >>= 1) p += __shfl_xor(p, off);
    if ((tid & 63) == 0) atomicAdd(&lg[c], p);
  }
  __syncthreads();
  if (tid == 0) {
    double m = lg[0];
#pragma unroll
    for (int c = 1; c < 10; ++c) m = lg[c] > m ? lg[c] : m;
    double sum = 0.0;
#pragma unroll
    for (int c = 0; c < 10; ++c) sum += exp(lg[c] - m);
    mred[0] = m;
    mred[1] = log(sum);
  }
  __syncthreads();
  if (tid < 10) {
    double o = lg[tid] - mred[0] - mred[1];
    if (isb)
      ((unsigned short*)out)[row * 10 + tid] = f2b((float)o);
    else
      ((float*)out)[row * 10 + tid] = (float)o;
  }
}

// ---------------- launch ----------------
extern "C" void kernel_launch(void* const* d_in, const int* in_sizes, int n_in,
                              void* d_out, int out_size, void* d_ws, size_t ws_size,
                              hipStream_t stream) {
  // ws layout (bytes):
  //   WtF   : 9216*1024*4 = 37,748,736  @ 0
  //   wpair : 4096*512*8  = 16,777,216  @ 37,748,736
  //   wcnt  : 4096*4      =     16,384  @ 54,525,952
  //   h     : 4096*1024*4 = 16,777,216  @ 54,542,336
  //   flag  : 4                         @ 71,319,552
  char* ws = (char*)d_ws;
  float* WtF = (float*)ws;
  int2* wpair = (int2*)(ws + 37748736);
  int* wcnt = (int*)(ws + 54525952);
  float* h = (float*)(ws + 54542336);
  int* flag = (int*)(ws + 71319552);

  k_detect<<<1, 64, 0, stream>>>(d_in[0], flag);
  k_prep<<<dim3(144, 16), 256, 0, stream>>>(d_in[4], d_in[5], WtF, flag);
  k_conv<<<4096, 256, 0, stream>>>(d_in[0], d_in[1], d_in[2], d_in[3],
                                   wpair, wcnt, flag);
  k_fc1<<<4096 * 8, 128, 0, stream>>>(WtF, wpair, wcnt, d_in[6], h, flag);
  k_sel<<<4096, 256, 0, stream>>>(h, d_in[7], d_in[8], d_in[9], d_out, flag);
}